// Round 6
// baseline (257.435 us; speedup 1.0000x reference)
//
#include <hip/hip_runtime.h>

// Weighted keypoint MSE loss:
//   oob = (tx<0)|(tx>1024)|(ty<0)|(ty>1024)
//   loss = sum( (oob ? 0.01 : 1.0) * ((ox-tx)^2 + (oy-ty)^2) ) / B
// Inputs: output [B,K,2] fp32, target [B,K,2] fp32, B=4096, K=4096. 268 MB read.
//
// R1-R3: ILP from source -> compiler re-serializes. 99.7 us.
// R4: nt target + normal output: 80 us (3.35 TB/s).
// R5: cur/next software pipeline -> collapsed by compiler. 82 us.
// R6: inline-asm 32-deep CONVOY (drain vmcnt(0)) -> 104 us. Burst-drain is
//     the wrong shape: memory system floods then idles.
// R7: partial-L3-retention split -> FETCH unchanged, 108 us. Retention
//     doesn't happen; mixed policy on one stream hurts.
// R8: all-nt BOTH streams -> ~70-73 us (fell out of rocprof top-5; harness
//     overhead ~180 us, bench 253). 268 MB at ~3.8 TB/s. Progression
//     2.69 -> 3.35 -> 3.8 TB/s tracks cache-mgmt overhead removal, not a
//     hard cap. Harness fillBuffer shows 6.9 TB/s write on the same run.
// R9 (this): last discriminating probe — ROLLING-WINDOW counted vmcnt
//     (AITER pattern: never drain to 0; R6 was a convoy, not a window).
//     8 unrolled steps x 4 loads; step s issues step s+1's loads, then
//     s_waitcnt vmcnt(4) + sched_barrier(0), then consumes step s. Constant
//     4-8 loads/wave in flight. Live window 2 steps -> ~56 VGPR, 8 waves/SIMD.
//     Predict: if issue-shape was the limiter -> 50-60 us (bench ~235).
//     If unchanged ~70 -> nt-read service cap confirmed; revert to R8 and
//     declare ROOFLINE next round.

#define WIDTH_F  1024.0f
#define HEIGHT_F 1024.0f
#define OOB_W    0.01f
#define NB 16        // float4 per array per thread (exact for bench shape)
#define NSTEP 8      // unrolled steps
#define PAIRS 2      // float4-pairs consumed per step (4 loads/step)

typedef float f32x4 __attribute__((ext_vector_type(4)));

// One global_load_dwordx4 with nt policy, 32-bit voffset + SGPR base.
#define LOADX4_NT(dst, base, voff)                                   \
    asm volatile("global_load_dwordx4 %0, %1, %2 nt"                 \
                 : "=&v"(dst) : "v"(voff), "s"(base))

__device__ __forceinline__ float kp_pair(f32x4 o, f32x4 t) {
    float dx = o[0] - t[0];
    float dy = o[1] - t[1];
    float sqA = dx * dx + dy * dy;
    bool oobA = (t[0] < 0.0f) || (t[0] > WIDTH_F) || (t[1] < 0.0f) || (t[1] > HEIGHT_F);
    float dz = o[2] - t[2];
    float dw = o[3] - t[3];
    float sqB = dz * dz + dw * dw;
    bool oobB = (t[2] < 0.0f) || (t[2] > WIDTH_F) || (t[3] < 0.0f) || (t[3] > HEIGHT_F);
    return (oobA ? OOB_W : 1.0f) * sqA + (oobB ? OOB_W : 1.0f) * sqB;
}

__global__ __launch_bounds__(256) void res_kp_loss_kernel(
    const f32x4* __restrict__ out4,
    const f32x4* __restrict__ tgt4,
    float* __restrict__ result,
    int n4,
    float inv_b) {
    const int idx    = blockIdx.x * blockDim.x + threadIdx.x;
    const int stride = gridDim.x * blockDim.x;

    float acc[4];
    acc[0] = acc[1] = acc[2] = acc[3] = 0.0f;

    int i = idx;
    if (idx + (NB - 1) * stride < n4) {
        f32x4 t[NB], o[NB];

        // ISSUE(s): 4 nt loads for step s (pairs 2s, 2s+1 of both arrays).
        #define ISSUE(s)                                                      \
            do {                                                              \
                unsigned v0 = (unsigned)(idx + (2 * (s)) * stride) * 16u;     \
                unsigned v1 = (unsigned)(idx + (2 * (s) + 1) * stride) * 16u; \
                LOADX4_NT(t[2 * (s)],     tgt4, v0);                          \
                LOADX4_NT(t[2 * (s) + 1], tgt4, v1);                          \
                LOADX4_NT(o[2 * (s)],     out4, v0);                          \
                LOADX4_NT(o[2 * (s) + 1], out4, v1);                          \
            } while (0)

        #define CONSUME(s)                                                    \
            do {                                                              \
                acc[(2 * (s)) & 3]     += kp_pair(o[2 * (s)],     t[2 * (s)]);\
                acc[(2 * (s) + 1) & 3] += kp_pair(o[2 * (s) + 1], t[2 * (s) + 1]); \
            } while (0)

        // Rolling window: steady state keeps 4-8 loads in flight, never 0.
        ISSUE(0);
        #pragma unroll
        for (int s = 0; s < NSTEP; ++s) {
            if (s + 1 < NSTEP) {
                // issue next step, then wait for CURRENT step only:
                // outstanding = 8, vmcnt(4) leaves next step's 4 in flight.
                switch (s + 1) {   // force compile-time ISSUE expansion
                    case 1: ISSUE(1); break;
                    case 2: ISSUE(2); break;
                    case 3: ISSUE(3); break;
                    case 4: ISSUE(4); break;
                    case 5: ISSUE(5); break;
                    case 6: ISSUE(6); break;
                    case 7: ISSUE(7); break;
                }
                asm volatile("s_waitcnt vmcnt(4)" ::: "memory");
            } else {
                asm volatile("s_waitcnt vmcnt(0)" ::: "memory");
            }
            // rule #18: stop hipcc hoisting the consume VALU past the wait.
            __builtin_amdgcn_sched_barrier(0);
            switch (s) {
                case 0: CONSUME(0); break;
                case 1: CONSUME(1); break;
                case 2: CONSUME(2); break;
                case 3: CONSUME(3); break;
                case 4: CONSUME(4); break;
                case 5: CONSUME(5); break;
                case 6: CONSUME(6); break;
                case 7: CONSUME(7); break;
            }
        }
        #undef ISSUE
        #undef CONSUME
        i = idx + NB * stride;
    }
    // Generic tail / fallback for non-bench shapes (dead for B=K=4096).
    for (; i < n4; i += stride)
        acc[0] += kp_pair(__builtin_nontemporal_load(&out4[i]),
                          __builtin_nontemporal_load(&tgt4[i]));

    float accs = (acc[0] + acc[1]) + (acc[2] + acc[3]);

    // wave-64 shuffle reduction
    #pragma unroll
    for (int off = 32; off > 0; off >>= 1)
        accs += __shfl_down(accs, off, 64);

    __shared__ float wave_sums[4];
    int lane = threadIdx.x & 63;
    int wave = threadIdx.x >> 6;
    if (lane == 0) wave_sums[wave] = accs;
    __syncthreads();

    if (threadIdx.x == 0) {
        float s = (wave_sums[0] + wave_sums[1]) + (wave_sums[2] + wave_sums[3]);
        atomicAdd(result, s * inv_b);  // device-scope by default on CDNA
    }
}

extern "C" void kernel_launch(void* const* d_in, const int* in_sizes, int n_in,
                              void* d_out, int out_size, void* d_ws, size_t ws_size,
                              hipStream_t stream) {
    const f32x4* out4 = (const f32x4*)d_in[0];  // output [B,K,2] fp32
    const f32x4* tgt4 = (const f32x4*)d_in[1];  // target [B,K,2] fp32
    float* result = (float*)d_out;

    const int total_floats = in_sizes[0];          // B*K*2 = 33,554,432
    const int n4 = total_floats / 4;               // 8,388,608 float4 per array
    const float inv_b = 1.0f / 4096.0f;            // B = 4096

    // d_out is poisoned 0xAA before every timed launch — zero it (async, capture-safe)
    hipMemsetAsync(d_out, 0, out_size * sizeof(float), stream);

    const int block = 256;
    const int grid = 2048;  // 16 float4 per thread per array; n4 = 16*stride
    res_kp_loss_kernel<<<grid, block, 0, stream>>>(out4, tgt4, result, n4, inv_b);
}